// Round 3
// baseline (39.326 us; speedup 1.0000x reference)
//
#include <hip/hip_runtime.h>

// Pool4d: x [b=2, c=8, l=16, d=32, h=64, w=64] f32
// kernel (3,3,3,3), stride (1,2,2,2), VALID, divide by 81.
// out [2, 8, 14, 15, 31, 31] f32.
//
// Fused single-pass, l-split in two halves for 2x TLP:
//   lh=0: spatial sums for frames 0..8  -> outputs lo 0..6
//   lh=1: spatial sums for frames 7..15 -> outputs lo 7..13
// w-window loaded as two aligned float2 (8B) instead of 3 scalar loads.

#define BC   16          // b*c
#define L_IN 16
#define D_IN 32
#define H_IN 64
#define W_IN 64
#define L_O  14
#define D_O  15
#define H_O  31
#define W_O  31
#define SP_OUT (D_O * H_O * W_O)     // 14415
#define SP_IN  (D_IN * H_IN * W_IN)  // 131072
#define NFR   9                      // frames per half
#define NLO   7                      // outputs per half

__global__ __launch_bounds__(256)
void pool4d_fused2(const float* __restrict__ x, float* __restrict__ out) {
    int idx = blockIdx.x * blockDim.x + threadIdx.x;
    const int total = BC * 2 * SP_OUT;      // 461,280
    if (idx >= total) return;
    int wo  = idx % W_O;
    int t   = idx / W_O;
    int ho  = t % H_O;
    t      /= H_O;
    int dd  = t % D_O;
    int rem = t / D_O;                      // [0, 32)
    int lh  = rem & 1;
    int bc  = rem >> 1;
    int l0  = lh * 7;                       // first frame of this half

    const float* xb = x + ((size_t)bc * L_IN + l0) * SP_IN
                        + (size_t)(2 * dd) * (H_IN * W_IN)
                        + (2 * ho) * W_IN + 2 * wo;

    // Spatial 3x3x3 sums for 9 consecutive frames (static indexing).
    float s[NFR];
    #pragma unroll
    for (int l = 0; l < NFR; ++l) {
        const float* fb = xb + (size_t)l * SP_IN;
        float acc = 0.0f;
        #pragma unroll
        for (int kd = 0; kd < 3; ++kd) {
            #pragma unroll
            for (int kh = 0; kh < 3; ++kh) {
                const float* p = fb + kd * (H_IN * W_IN) + kh * W_IN;
                float2 a = *reinterpret_cast<const float2*>(p);      // w, w+1 (8B aligned)
                float  b = p[2];                                      // w+2
                acc += a.x + a.y + b;
            }
        }
        s[l] = acc;
    }

    // Temporal sliding window (k=3, stride=1) + scale.
    int sp = (dd * H_O + ho) * W_O + wo;
    float* op = out + ((size_t)bc * L_O + l0) * SP_OUT + sp;
    const float inv = 1.0f / 81.0f;
    #pragma unroll
    for (int lo = 0; lo < NLO; ++lo)
        op[(size_t)lo * SP_OUT] = (s[lo] + s[lo + 1] + s[lo + 2]) * inv;
}

extern "C" void kernel_launch(void* const* d_in, const int* in_sizes, int n_in,
                              void* d_out, int out_size, void* d_ws, size_t ws_size,
                              hipStream_t stream) {
    const float* x = (const float*)d_in[0];
    float* out = (float*)d_out;
    (void)d_ws; (void)ws_size;

    int total = BC * 2 * SP_OUT;
    int block = 256;
    int grid = (total + block - 1) / block;
    pool4d_fused2<<<grid, block, 0, stream>>>(x, out);
}

// Round 4
// 28.158 us; speedup vs baseline: 1.3967x; 1.3967x over previous
//
#include <hip/hip_runtime.h>

// Pool4d: x [b=2, c=8, l=16, d=32, h=64, w=64] f32
// kernel (3,3,3,3), stride (1,2,2,2), VALID, divide by 81.
// out [2, 8, 14, 15, 31, 31] f32.
//
// Fused single-pass (R2 structure): one thread per output spatial site,
// loops all 16 l-frames, emits 14 temporal outputs.
// + XCD-chunked bijective blockIdx swizzle (dd/ho-neighbor blocks share
//   d-planes/h-rows -> keep them on the same XCD L2; kills the 1.5x
//   d-dimension HBM over-fetch).
// + non-temporal output stores (don't evict reusable input from L2).

#define BC   16          // b*c
#define L_IN 16
#define D_IN 32
#define H_IN 64
#define W_IN 64
#define L_O  14
#define D_O  15
#define H_O  31
#define W_O  31
#define SP_OUT (D_O * H_O * W_O)     // 14415
#define SP_IN  (D_IN * H_IN * W_IN)  // 131072
#define NXCD 8

__global__ __launch_bounds__(256)
void pool4d_fused_swz(const float* __restrict__ x, float* __restrict__ out) {
    // Bijective XCD-chunked swizzle (m204): hardware round-robins blockIdx
    // across XCDs; remap so each XCD processes a contiguous chunk of work.
    int nwg = gridDim.x;
    int xcd = blockIdx.x % NXCD;
    int pos = blockIdx.x / NXCD;
    int q = nwg / NXCD, r = nwg % NXCD;
    int wg = (xcd < r ? xcd * (q + 1) : r * (q + 1) + (xcd - r) * q) + pos;

    int idx = wg * blockDim.x + threadIdx.x;
    const int total = BC * SP_OUT;          // 230,640
    if (idx >= total) return;
    int wo = idx % W_O;
    int t  = idx / W_O;
    int ho = t % H_O;
    t     /= H_O;
    int dd = t % D_O;
    int bc = t / D_O;

    const float* xb = x + (size_t)bc * L_IN * SP_IN
                        + (size_t)(2 * dd) * (H_IN * W_IN)
                        + (2 * ho) * W_IN + 2 * wo;

    // Spatial 3x3x3 sums for all 16 frames (static indexing).
    float s[L_IN];
    #pragma unroll
    for (int l = 0; l < L_IN; ++l) {
        const float* fb = xb + (size_t)l * SP_IN;
        float acc = 0.0f;
        #pragma unroll
        for (int kd = 0; kd < 3; ++kd) {
            #pragma unroll
            for (int kh = 0; kh < 3; ++kh) {
                const float* p = fb + kd * (H_IN * W_IN) + kh * W_IN;
                float2 a = *reinterpret_cast<const float2*>(p);  // 8B aligned (w even)
                acc += a.x + a.y + p[2];
            }
        }
        s[l] = acc;
    }

    // Temporal sliding window (k=3, stride=1) + scale; streaming stores.
    int sp = (dd * H_O + ho) * W_O + wo;
    float* op = out + (size_t)bc * L_O * SP_OUT + sp;
    const float inv = 1.0f / 81.0f;
    #pragma unroll
    for (int lo = 0; lo < L_O; ++lo)
        __builtin_nontemporal_store((s[lo] + s[lo + 1] + s[lo + 2]) * inv,
                                    &op[(size_t)lo * SP_OUT]);
}

extern "C" void kernel_launch(void* const* d_in, const int* in_sizes, int n_in,
                              void* d_out, int out_size, void* d_ws, size_t ws_size,
                              hipStream_t stream) {
    const float* x = (const float*)d_in[0];
    float* out = (float*)d_out;
    (void)d_ws; (void)ws_size;

    int total = BC * SP_OUT;
    int block = 256;
    int grid = (total + block - 1) / block;   // 901
    pool4d_fused_swz<<<grid, block, 0, stream>>>(x, out);
}